// Round 14
// baseline (477.238 us; speedup 1.0000x reference)
//
#include <hip/hip_runtime.h>
#include <hip/hip_fp16.h>
#include <math.h>

#define NN 100000
#define EE 1600000
#define ET 1700000   // EE + NN self loops
#define NEG 0.2f
#define PCH 8192     // edges per partition block
#define NPB 208      // ceil(ET/PCH)
#define NBKT 196     // 512-dst buckets: ceil(NN/512)
#define BSLOT 11264  // per-bucket slot capacity (mean 8704, +28 sigma)
#define G1B 1563     // gemm1m blocks = (NN+63)/64
#define A1B 3125     // alpha1h blocks = NN*8/256

typedef _Float16 half8_t __attribute__((ext_vector_type(8)));
typedef _Float16 h2_t __attribute__((ext_vector_type(2)));
typedef float f32x4 __attribute__((ext_vector_type(4)));

static_assert(NN % 16 == 0, "aggB1 grid exactness");
static_assert(NN % 8 == 0, "aggB2 grid exactness");
static_assert((NN * 8) % 256 == 0, "alpha1h grid exactness");
static_assert((NN + 511) / 512 == NBKT, "bucket count");

// ---------------- ws layout (bytes) ----------------
// bkt (NBKT*BSLOT u64 = 17.7MB) aliases the head of aggh (102.4MB): bkt's
// last read (k_bsort) precedes aggh's first write (k_aggB2).
static constexpr size_t alignup(size_t x) { return (x + 255) & ~(size_t)255; }
static constexpr size_t OFF_H1H  = 0;                                    // N*64 fp16
static constexpr size_t OFF_HELU = alignup(OFF_H1H  + (size_t)NN*64*2);  // N*64 fp16
static constexpr size_t OFF_AS1H = alignup(OFF_HELU + (size_t)NN*64*2);  // N*8 fp16
static constexpr size_t OFF_AD1  = alignup(OFF_AS1H + (size_t)NN*8*2);   // N*8 f32
static constexpr size_t OFF_AS2H = alignup(OFF_AD1  + (size_t)NN*8*4);   // N*8 fp16
static constexpr size_t OFF_AD2  = alignup(OFF_AS2H + (size_t)NN*8*2);   // N*8 f32
static constexpr size_t OFF_WSD2 = alignup(OFF_AD2  + (size_t)NN*8*4);   // 64*16 f32
static constexpr size_t OFF_W2T  = alignup(OFF_WSD2 + 64*16*4);          // 64*512 fp16
static constexpr size_t OFF_W1T  = alignup(OFF_W2T  + 64*512*2);         // 64*256 fp16
static constexpr size_t OFF_BBAS = alignup(OFF_W1T  + 64*256*2);         // 256 int
static constexpr size_t OFF_RP   = alignup(OFF_BBAS + 256*4);            // (NN+1) int
static constexpr size_t OFF_SRC  = alignup(OFF_RP   + (size_t)(NN+1)*4); // ET int
static constexpr size_t OFF_BCUR = alignup(OFF_SRC  + (size_t)ET*4);     // 256*16 int (64B-padded)
static constexpr size_t OFF_AGGH = alignup(OFF_BCUR + 256*16*4);         // N*512 fp16
static constexpr size_t OFF_BKT  = OFF_AGGH;                             // alias (disjoint lifetime)
static_assert((size_t)NBKT * BSLOT * 8 <= (size_t)NN * 512 * 2, "bkt fits in aggh");

__device__ inline void unpack8(float4 raw, float* g) {
  __half2* hp = (__half2*)&raw;
  float2 a = __half22float2(hp[0]); g[0] = a.x; g[1] = a.y;
  float2 b = __half22float2(hp[1]); g[2] = b.x; g[3] = b.y;
  float2 c = __half22float2(hp[2]); g[4] = c.x; g[5] = c.y;
  float2 d = __half22float2(hp[3]); g[6] = d.x; g[7] = d.y;
}

// half-pair builders: (b.lo, a.lo) and (b.hi, a.hi)
__device__ inline unsigned permb_lo(unsigned a, unsigned b) {
#if __has_builtin(__builtin_amdgcn_perm)
  return __builtin_amdgcn_perm(a, b, 0x05040100u);
#else
  return (b & 0xffffu) | (a << 16);
#endif
}
__device__ inline unsigned permb_hi(unsigned a, unsigned b) {
#if __has_builtin(__builtin_amdgcn_perm)
  return __builtin_amdgcn_perm(a, b, 0x07060302u);
#else
  return (b >> 16) | (a & 0xffff0000u);
#endif
}

// dot2: c + w.lo*g.lo + w.hi*g.hi  (f16 inputs, f32 accumulate)
__device__ inline float dot2h(unsigned w, unsigned g, float c) {
#if __has_builtin(__builtin_amdgcn_fdot2)
  union { unsigned u; h2_t h; } uw, ug;
  uw.u = w; ug.u = g;
  return __builtin_amdgcn_fdot2(uw.h, ug.h, c, false);
#else
  union { unsigned u; __half2 h; } uw, ug;
  uw.u = w; ug.u = g;
  float2 fw = __half22float2(uw.h), fg = __half22float2(ug.h);
  return c + fw.x * fg.x + fw.y * fg.y;
#endif
}

// ---------------- fused prep: W1t + W2t + wsd2 + bcur init -------------------
__global__ void k_prep(const float* __restrict__ W1, const float* __restrict__ W2,
                       const float* __restrict__ a_src2, const float* __restrict__ a_dst2,
                       _Float16* __restrict__ W1t, _Float16* __restrict__ W2t,
                       float* __restrict__ wsd2, int* __restrict__ bcur) {
  int t = blockIdx.x * 256 + threadIdx.x;
  if (t < 64 * 256) {
    int f = t >> 8, k = t & 255;
    W1t[t] = (_Float16)W1[k * 64 + f];
  }
  {
    int f = t >> 9, k = t & 511;
    int h = k >> 6, kk = k & 63;
    W2t[t] = (_Float16)W2[kk * 512 + h * 64 + f];
  }
  if (t < 1024) {
    int k = t >> 4, j = t & 15, h = j & 7;
    const float* av = (j < 8) ? a_src2 : a_dst2;
    float s = 0.f;
    for (int f = 0; f < 64; f++) s += W2[k * 512 + h * 64 + f] * av[h * 64 + f];
    wsd2[t] = s;
  }
  if (t < 256) bcur[t * 16] = t * BSLOT;   // per-bucket slot base, 64B-padded
}

// ---------------- F1: edge-partition (blocks 0..NPB) || GEMM1 (rest) --------
__global__ __launch_bounds__(256) void k_f1(const float* __restrict__ x,
                                            const _Float16* __restrict__ W1t,
                                            __half* __restrict__ h1h,
                                            const int* __restrict__ edge,
                                            int* __restrict__ bcur,
                                            unsigned long long* __restrict__ bkt) {
  if (blockIdx.x < NPB) {
    // ---- edge partition into 196 x 512-dst buckets ----
    __shared__ int lcnt[256];
    __shared__ int lbase[256];
    __shared__ int loff[256];
    const int t = threadIdx.x;
    const int e0 = blockIdx.x * PCH;
    lcnt[t] = 0; loff[t] = 0;
    __syncthreads();
    for (int i = t; i < PCH; i += 256) {
      int e = e0 + i;
      if (e >= ET) break;
      int d = (e < EE) ? edge[EE + e] : (e - EE);
      atomicAdd(&lcnt[d >> 9], 1);
    }
    __syncthreads();
    if (lcnt[t] > 0) lbase[t] = atomicAdd(&bcur[t * 16], lcnt[t]);
    __syncthreads();
    for (int i = t; i < PCH; i += 256) {
      int e = e0 + i;
      if (e >= ET) break;
      int s, d;
      if (e < EE) { s = edge[e]; d = edge[EE + e]; } else { s = e - EE; d = s; }
      int b = d >> 9;
      int off = atomicAdd(&loff[b], 1);
      bkt[(size_t)lbase[b] + off] = ((unsigned long long)d << 32) | (unsigned)s;
    }
    return;
  }
  // ---- gemm1m body ----
  const int bid = blockIdx.x - NPB;
  const int lane = threadIdx.x & 63;
  const int wv = threadIdx.x >> 6;
  const int m16 = lane & 15;
  const int q = lane >> 4;
  const int row = bid * 64 + wv * 16 + m16;
  const bool rok = row < NN;
  const float* xr = x + (size_t)row * 256 + q * 8;
  f32x4 c0 = {0.f, 0.f, 0.f, 0.f}, c1 = c0, c2 = c0, c3 = c0;
#pragma unroll
  for (int k0 = 0; k0 < 256; k0 += 32) {
    half8_t a;
    if (rok) {
      float4 xa = ((const float4*)(xr + k0))[0];
      float4 xb = ((const float4*)(xr + k0))[1];
      a[0] = (_Float16)xa.x; a[1] = (_Float16)xa.y;
      a[2] = (_Float16)xa.z; a[3] = (_Float16)xa.w;
      a[4] = (_Float16)xb.x; a[5] = (_Float16)xb.y;
      a[6] = (_Float16)xb.z; a[7] = (_Float16)xb.w;
    } else {
#pragma unroll
      for (int i = 0; i < 8; i++) a[i] = (_Float16)0.f;
    }
    half8_t b0 = *((const half8_t*)(W1t + (size_t)(0 * 16 + m16) * 256 + k0 + q * 8));
    half8_t b1 = *((const half8_t*)(W1t + (size_t)(1 * 16 + m16) * 256 + k0 + q * 8));
    half8_t b2 = *((const half8_t*)(W1t + (size_t)(2 * 16 + m16) * 256 + k0 + q * 8));
    half8_t b3 = *((const half8_t*)(W1t + (size_t)(3 * 16 + m16) * 256 + k0 + q * 8));
    c0 = __builtin_amdgcn_mfma_f32_16x16x32_f16(a, b0, c0, 0, 0, 0);
    c1 = __builtin_amdgcn_mfma_f32_16x16x32_f16(a, b1, c1, 0, 0, 0);
    c2 = __builtin_amdgcn_mfma_f32_16x16x32_f16(a, b2, c2, 0, 0, 0);
    c3 = __builtin_amdgcn_mfma_f32_16x16x32_f16(a, b3, c3, 0, 0, 0);
  }
#pragma unroll
  for (int r = 0; r < 4; r++) {
    int orow = bid * 64 + wv * 16 + q * 4 + r;
    if (orow >= NN) continue;
    __half* op = h1h + (size_t)orow * 64;
    op[0 * 16 + m16] = __float2half(c0[r]);
    op[1 * 16 + m16] = __float2half(c1[r]);
    op[2 * 16 + m16] = __float2half(c2[r]);
    op[3 * 16 + m16] = __float2half(c3[r]);
  }
}

// ---------------- F2: alpha1h (blocks 0..A1B) || bucket prefix (last block) --
__global__ __launch_bounds__(256) void k_f2(const __half* __restrict__ h1h,
                                            const float* __restrict__ a_src1,
                                            const float* __restrict__ a_dst1,
                                            __half* __restrict__ as1h,
                                            float* __restrict__ ad1,
                                            const int* __restrict__ bcur,
                                            int* __restrict__ bbase) {
  if (blockIdx.x == A1B) {
    // ---- binpfx body: cnt_c = bcur[c*16] - c*BSLOT ----
    int t = threadIdx.x;
    if (t > NBKT) return;
    int run = 0;
    for (int c = 0; c < NBKT; c++)
      if (c < t) run += bcur[c * 16] - c * BSLOT;
    bbase[t] = run;            // bbase[NBKT] = ET
    return;
  }
  int g = blockIdx.x * 256 + threadIdx.x;
  int n = g >> 3, h = g & 7;
  float4 raw = *((const float4*)&h1h[(size_t)n * 64 + h * 8]);
  float v[8];
  unpack8(raw, v);
  float s = 0.f, d = 0.f;
#pragma unroll
  for (int f = 0; f < 8; f++) {
    s += v[f] * a_src1[h * 8 + f];
    d += v[f] * a_dst1[h * 8 + f];
  }
  as1h[g] = __float2half(s);
  ad1[g] = d;
}

// ---------------- per-bucket LDS finalize -> rp + ssrc ----------------------
// 196 blocks x 512 threads, 512 dsts each (2x parallelism vs 128x1024).
__global__ __launch_bounds__(512) void k_bsort(const unsigned long long* __restrict__ bkt,
                                               const int* __restrict__ bbase,
                                               int* __restrict__ rp,
                                               int* __restrict__ ssrc) {
  __shared__ int lh[512];
  __shared__ int lc[512];
  const int t = threadIdx.x;
  const int b = blockIdx.x;             // 0..NBKT-1
  const int base = bbase[b];
  const int cnt = bbase[b + 1] - base;
  const size_t bin = (size_t)b * BSLOT;
  const int d0 = b << 9;
  lh[t] = 0;
  __syncthreads();
  for (int i = t; i < cnt; i += 512)
    atomicAdd(&lh[(int)(bkt[bin + i] >> 32) - d0], 1);
  __syncthreads();
  int v = lh[t];                        // this dst's count
  for (int off = 1; off < 512; off <<= 1) {
    __syncthreads();
    int a = (t >= off) ? lh[t - off] : 0;
    __syncthreads();
    lh[t] += a;
  }
  __syncthreads();
  int excl = base + lh[t] - v;          // exclusive prefix (global position)
  lc[t] = excl;
  int d = d0 + t;
  if (d < NN) rp[d] = excl;
  if (b == 0 && t == 0) rp[NN] = ET;
  __syncthreads();
  for (int i = t; i < cnt; i += 512) {
    unsigned long long e = bkt[bin + i];
    int pos = atomicAdd(&lc[(int)(e >> 32) - d0], 1);
    ssrc[pos] = (int)(e & 0xffffffffu);
  }
}

// ---------------- layer-1 aggregation: 16 lanes per dst, 8-edge chunks ------
// (round-7 structure, byte-identical: measured best for aggB1)
__global__ __launch_bounds__(256) void k_aggB1(
    const __half* __restrict__ h1h, const __half* __restrict__ as1h,
    const float* __restrict__ ad1, const float* __restrict__ b1,
    const int* __restrict__ rp, const int* __restrict__ ssrc,
    const float* __restrict__ wsd2,
    __half* __restrict__ heluh, __half* __restrict__ as2h, float* __restrict__ ad2) {
  __shared__ float lds_w[1024];     // wsd2 staged once per block
  __shared__ float lds_v[16][68];   // per-group ELU output (padded)
  const int t = threadIdx.x;
  const int lane = t & 63;
  const int wv = t >> 6;
  const int gl = lane & 15;
  const int grp = lane >> 4;
  const int gi = wv * 4 + grp;
  const int d = blockIdx.x * 16 + gi;    // grid is exactly NN/16 -> no guard
#pragma unroll
  for (int i = 0; i < 4; i++) lds_w[t + i * 256] = wsd2[t + i * 256];
  __syncthreads();
  const int h = gl >> 1;                 // head owned by this lane
  const int hsrc = (lane & 48) | h;      // group-base | head lane
  const float adv = (gl < 8) ? ad1[d * 8 + gl] : 0.f;
  const int r0 = rp[d], r1 = rp[d + 1];
  float acc0 = 0.f, acc1 = 0.f, acc2 = 0.f, acc3 = 0.f;
  float lsum = 0.f;
  const __half* gp = h1h + gl * 4;
  const __half* ap = as1h + gl;
  for (int e = r0; e < r1; e += 8) {
    int ss[8];
#pragma unroll
    for (int k = 0; k < 8; k++) {
      int idx = e + k;
      ss[k] = ssrc[(idx < r1) ? idx : (r1 - 1)];
    }
    union { float2 f; unsigned u[2]; } raws[8];
#pragma unroll
    for (int k = 0; k < 8; k++) raws[k].f = *((const float2*)(gp + (size_t)ss[k] * 64));
    unsigned wp[4];
    if (gl < 8) {
      float pv[8];
#pragma unroll
      for (int k = 0; k < 8; k++) {
        float tt = __half2float(ap[ss[k] * 8]) + adv;
        tt = tt > 0.f ? tt : NEG * tt;
        pv[k] = (e + k < r1) ? __expf(tt) : 0.f;
      }
#pragma unroll
      for (int j = 0; j < 4; j++) {
        __half2 ph = __floats2half2_rn(pv[2 * j], pv[2 * j + 1]);
        union { __half2 h2; unsigned u; } uw; uw.h2 = ph;
        wp[j] = uw.u;
        float2 pb = __half22float2(ph);
        lsum += pb.x + pb.y;
      }
    } else {
#pragma unroll
      for (int j = 0; j < 4; j++) wp[j] = 0;
    }
#pragma unroll
    for (int j = 0; j < 4; j++) {
      unsigned w = (unsigned)__shfl((int)wp[j], hsrc, 64);
      unsigned pr0 = permb_lo(raws[2 * j + 1].u[0], raws[2 * j].u[0]);
      unsigned pr1 = permb_hi(raws[2 * j + 1].u[0], raws[2 * j].u[0]);
      unsigned pr2 = permb_lo(raws[2 * j + 1].u[1], raws[2 * j].u[1]);
      unsigned pr3 = permb_hi(raws[2 * j + 1].u[1], raws[2 * j].u[1]);
      acc0 = dot2h(w, pr0, acc0);
      acc1 = dot2h(w, pr1, acc1);
      acc2 = dot2h(w, pr2, acc2);
      acc3 = dot2h(w, pr3, acc3);
    }
  }
  float lv = __shfl(lsum, hsrc, 64);
  float rl = 1.f / lv;
  float v0 = acc0 * rl + b1[gl * 4 + 0];
  float v1 = acc1 * rl + b1[gl * 4 + 1];
  float v2 = acc2 * rl + b1[gl * 4 + 2];
  float v3 = acc3 * rl + b1[gl * 4 + 3];
  v0 = v0 > 0.f ? v0 : __expf(v0) - 1.f;   // ELU
  v1 = v1 > 0.f ? v1 : __expf(v1) - 1.f;
  v2 = v2 > 0.f ? v2 : __expf(v2) - 1.f;
  v3 = v3 > 0.f ? v3 : __expf(v3) - 1.f;
  union { __half2 h2[2]; float2 f2; } u;
  u.h2[0] = __floats2half2_rn(v0, v1);
  u.h2[1] = __floats2half2_rn(v2, v3);
  *((float2*)&heluh[(size_t)d * 64 + gl * 4]) = u.f2;
  lds_v[gi][gl * 4 + 0] = v0;
  lds_v[gi][gl * 4 + 1] = v1;
  lds_v[gi][gl * 4 + 2] = v2;
  lds_v[gi][gl * 4 + 3] = v3;
  float dot = 0.f;
#pragma unroll
  for (int f = 0; f < 64; f++) dot += lds_v[gi][f] * lds_w[f * 16 + gl];
  if (gl < 8) as2h[d * 8 + gl] = __float2half(dot);
  else        ad2[d * 8 + (gl & 7)] = dot;
}

// ---------------- layer-2 aggregation: 32 lanes per dst, 1-deep pipeline ----
// (round-7 structure, byte-identical: measured best)
__global__ __launch_bounds__(256) void k_aggB2(
    const __half* __restrict__ heluh, const __half* __restrict__ as2h,
    const float* __restrict__ ad2, const int* __restrict__ rp,
    const int* __restrict__ ssrc, __half* __restrict__ aggh) {
  const int lane = threadIdx.x & 63;
  const int wv = threadIdx.x >> 6;
  const int gl = lane & 31;
  const int fl = gl & 15;
  const int hh = (gl >> 4) * 4;          // head base: 0 or 4
  const int gb = lane & 32;              // group-base lane
  const int d = blockIdx.x * 8 + wv * 2 + (lane >> 5);  // grid exactly NN/8
  const float adv = (gl < 8) ? ad2[d * 8 + gl] : 0.f;
  const int r0 = rp[d], r1 = rp[d + 1];  // r1 > r0 always (self-loop)
  float acc[4][4];
#pragma unroll
  for (int j = 0; j < 4; j++)
#pragma unroll
    for (int k = 0; k < 4; k++) acc[j][k] = 0.f;
  float lsum = 0.f;
  const __half* gp = heluh + fl * 4;
  const __half* ap = as2h + gl;
  int s1c = min(r0 + 1, r1 - 1);
  union { float2 f; unsigned u[2]; } raw0, raw1, r0n, r1n;
  raw0.f = *((const float2*)(gp + (size_t)ssrc[r0] * 64));
  raw1.f = *((const float2*)(gp + (size_t)ssrc[s1c] * 64));
  __half lg0 = __float2half(0.f), lg1 = lg0, lg0n = lg0, lg1n = lg0;
  if (gl < 8) { lg0 = ap[(size_t)ssrc[r0] * 8]; lg1 = ap[(size_t)ssrc[s1c] * 8]; }
  for (int e = r0; e < r1; e += 2) {
    int np = e + 2;
    if (np < r1) {
      int sn0 = ssrc[np];
      int sn1 = ssrc[min(np + 1, r1 - 1)];
      r0n.f = *((const float2*)(gp + (size_t)sn0 * 64));
      r1n.f = *((const float2*)(gp + (size_t)sn1 * 64));
      if (gl < 8) { lg0n = ap[(size_t)sn0 * 8]; lg1n = ap[(size_t)sn1 * 8]; }
    }
    unsigned wpack = 0;
    if (gl < 8) {
      float t0 = __half2float(lg0) + adv;
      float t1 = __half2float(lg1) + adv;
      t0 = t0 > 0.f ? t0 : NEG * t0;
      t1 = t1 > 0.f ? t1 : NEG * t1;
      float p0 = __expf(t0);
      float p1 = (e + 1 < r1) ? __expf(t1) : 0.f;
      __half2 ph = __floats2half2_rn(p0, p1);
      union { __half2 h2; unsigned u; } uw; uw.h2 = ph;
      wpack = uw.u;
      float2 pb = __half22float2(ph);
      lsum += pb.x + pb.y;
    }
    unsigned pr0 = permb_lo(raw1.u[0], raw0.u[0]);  // (g0 f0, g1 f0)
    unsigned pr1 = permb_hi(raw1.u[0], raw0.u[0]);
    unsigned pr2 = permb_lo(raw1.u[1], raw0.u[1]);
    unsigned pr3 = permb_hi(raw1.u[1], raw0.u[1]);
#pragma unroll
    for (int j = 0; j < 4; j++) {
      unsigned w = (unsigned)__shfl((int)wpack, gb | (hh + j), 64);
      acc[j][0] = dot2h(w, pr0, acc[j][0]);
      acc[j][1] = dot2h(w, pr1, acc[j][1]);
      acc[j][2] = dot2h(w, pr2, acc[j][2]);
      acc[j][3] = dot2h(w, pr3, acc[j][3]);
    }
    raw0 = r0n; raw1 = r1n; lg0 = lg0n; lg1 = lg1n;
  }
#pragma unroll
  for (int j = 0; j < 4; j++) {
    float lv = __shfl(lsum, gb | (hh + j), 64);
    float rl = 1.f / lv;
    union { __half2 h2[2]; float2 f2; } u;
    u.h2[0] = __floats2half2_rn(acc[j][0] * rl, acc[j][1] * rl);
    u.h2[1] = __floats2half2_rn(acc[j][2] * rl, acc[j][3] * rl);
    *((float2*)&aggh[(size_t)d * 512 + (hh + j) * 64 + fl * 4]) = u.f2;
  }
}

// ---------------- GEMM2 via MFMA: out = (1/8)*aggh[N,512] @ W2t^T + b2 -------
__global__ __launch_bounds__(256) void k_gemm2m(const __half* __restrict__ aggh,
                                                const _Float16* __restrict__ W2t,
                                                const float* __restrict__ b2,
                                                float* __restrict__ out) {
  const int lane = threadIdx.x & 63;
  const int wv = threadIdx.x >> 6;
  const int m16 = lane & 15;
  const int q = lane >> 4;
  const int row = blockIdx.x * 64 + wv * 16 + m16;
  const bool rok = row < NN;
  const _Float16* arow = (const _Float16*)aggh + (size_t)row * 512 + q * 8;
  half8_t zero8;
#pragma unroll
  for (int i = 0; i < 8; i++) zero8[i] = (_Float16)0.f;
  f32x4 c0 = {0.f, 0.f, 0.f, 0.f}, c1 = c0, c2 = c0, c3 = c0;
#pragma unroll
  for (int k0 = 0; k0 < 512; k0 += 32) {
    half8_t a = rok ? *((const half8_t*)(arow + k0)) : zero8;
    half8_t b0 = *((const half8_t*)(W2t + (size_t)(0 * 16 + m16) * 512 + k0 + q * 8));
    half8_t b1 = *((const half8_t*)(W2t + (size_t)(1 * 16 + m16) * 512 + k0 + q * 8));
    half8_t b2f = *((const half8_t*)(W2t + (size_t)(2 * 16 + m16) * 512 + k0 + q * 8));
    half8_t b3 = *((const half8_t*)(W2t + (size_t)(3 * 16 + m16) * 512 + k0 + q * 8));
    c0 = __builtin_amdgcn_mfma_f32_16x16x32_f16(a, b0, c0, 0, 0, 0);
    c1 = __builtin_amdgcn_mfma_f32_16x16x32_f16(a, b1, c1, 0, 0, 0);
    c2 = __builtin_amdgcn_mfma_f32_16x16x32_f16(a, b2f, c2, 0, 0, 0);
    c3 = __builtin_amdgcn_mfma_f32_16x16x32_f16(a, b3, c3, 0, 0, 0);
  }
  float bias0 = b2[0 * 16 + m16];
  float bias1 = b2[1 * 16 + m16];
  float bias2 = b2[2 * 16 + m16];
  float bias3 = b2[3 * 16 + m16];
#pragma unroll
  for (int r = 0; r < 4; r++) {
    int orow = blockIdx.x * 64 + wv * 16 + q * 4 + r;
    if (orow >= NN) continue;
    float* op = out + (size_t)orow * 64;
    op[0 * 16 + m16] = 0.125f * c0[r] + bias0;
    op[1 * 16 + m16] = 0.125f * c1[r] + bias1;
    op[2 * 16 + m16] = 0.125f * c2[r] + bias2;
    op[3 * 16 + m16] = 0.125f * c3[r] + bias3;
  }
}

extern "C" void kernel_launch(void* const* d_in, const int* in_sizes, int n_in,
                              void* d_out, int out_size, void* d_ws, size_t ws_size,
                              hipStream_t stream) {
  const float* x      = (const float*)d_in[0];
  const float* W1     = (const float*)d_in[1];
  const float* a_src1 = (const float*)d_in[2];
  const float* a_dst1 = (const float*)d_in[3];
  const float* b1     = (const float*)d_in[4];
  const float* W2     = (const float*)d_in[5];
  const float* a_src2 = (const float*)d_in[6];
  const float* a_dst2 = (const float*)d_in[7];
  const float* b2     = (const float*)d_in[8];
  const int*   edge   = (const int*)d_in[9];

  char* ws = (char*)d_ws;
  __half* h1h   = (__half*)(ws + OFF_H1H);
  __half* heluh = (__half*)(ws + OFF_HELU);
  __half* as1h  = (__half*)(ws + OFF_AS1H);
  float*  ad1   = (float*)(ws + OFF_AD1);
  __half* as2h  = (__half*)(ws + OFF_AS2H);
  float*  ad2   = (float*)(ws + OFF_AD2);
  float*  wsd2  = (float*)(ws + OFF_WSD2);
  _Float16* W2t = (_Float16*)(ws + OFF_W2T);
  _Float16* W1t = (_Float16*)(ws + OFF_W1T);
  int* bbase  = (int*)(ws + OFF_BBAS);
  int* rp     = (int*)(ws + OFF_RP);
  int* ssrc   = (int*)(ws + OFF_SRC);
  int* bcur   = (int*)(ws + OFF_BCUR);
  unsigned long long* bkt = (unsigned long long*)(ws + OFF_BKT);
  __half* aggh = (__half*)(ws + OFF_AGGH);
  float* out  = (float*)d_out;

  k_prep<<<128, 256, 0, stream>>>(W1, W2, a_src2, a_dst2, W1t, W2t, wsd2, bcur);
  k_f1<<<NPB + G1B, 256, 0, stream>>>(x, W1t, h1h, edge, bcur, bkt);
  k_f2<<<A1B + 1, 256, 0, stream>>>(h1h, a_src1, a_dst1, as1h, ad1, bcur, bbase);
  k_bsort<<<NBKT, 512, 0, stream>>>(bkt, bbase, rp, ssrc);
  k_aggB1<<<NN / 16, 256, 0, stream>>>(h1h, as1h, ad1, b1, rp, ssrc, wsd2, heluh, as2h, ad2);
  k_aggB2<<<NN / 8, 256, 0, stream>>>(heluh, as2h, ad2, rp, ssrc, aggh);
  k_gemm2m<<<(NN + 63) / 64, 256, 0, stream>>>(aggh, W2t, b2, out);
}

// Round 15
// 439.558 us; speedup vs baseline: 1.0857x; 1.0857x over previous
//
#include <hip/hip_runtime.h>
#include <hip/hip_fp16.h>
#include <math.h>

#define NN 100000
#define EE 1600000
#define ET 1700000   // EE + NN self loops
#define NEG 0.2f
#define PCH 8192     // edges per partition block
#define NPB 208      // ceil(ET/PCH)
#define BSLOT 20480  // per-bucket slot capacity (mean 17408 over 98 live buckets, +24 sigma)
#define G1B 1563     // gemm1m blocks = (NN+63)/64
#define A1B 3125     // alpha1h blocks = NN*8/256

typedef _Float16 half8_t __attribute__((ext_vector_type(8)));
typedef _Float16 h2_t __attribute__((ext_vector_type(2)));
typedef float f32x4 __attribute__((ext_vector_type(4)));

static_assert(NN % 16 == 0, "aggB1 grid exactness");
static_assert(NN % 8 == 0, "aggB2 grid exactness");
static_assert((NN * 8) % 256 == 0, "alpha1h grid exactness");

// ---------------- ws layout (bytes) ----------------
// bkt (128*BSLOT u64 = 21MB) aliases the head of aggh (102.4MB): bkt's last
// read (k_bsort) precedes aggh's first write (k_aggB2). Total ws ~145MB.
static constexpr size_t alignup(size_t x) { return (x + 255) & ~(size_t)255; }
static constexpr size_t OFF_H1H  = 0;                                    // N*64 fp16
static constexpr size_t OFF_HELU = alignup(OFF_H1H  + (size_t)NN*64*2);  // N*64 fp16
static constexpr size_t OFF_AS1H = alignup(OFF_HELU + (size_t)NN*64*2);  // N*8 fp16
static constexpr size_t OFF_AD1  = alignup(OFF_AS1H + (size_t)NN*8*2);   // N*8 f32
static constexpr size_t OFF_AS2H = alignup(OFF_AD1  + (size_t)NN*8*4);   // N*8 fp16
static constexpr size_t OFF_AD2  = alignup(OFF_AS2H + (size_t)NN*8*2);   // N*8 f32
static constexpr size_t OFF_WSD2 = alignup(OFF_AD2  + (size_t)NN*8*4);   // 64*16 f32
static constexpr size_t OFF_W2T  = alignup(OFF_WSD2 + 64*16*4);          // 64*512 fp16
static constexpr size_t OFF_W1T  = alignup(OFF_W2T  + 64*512*2);         // 64*256 fp16
static constexpr size_t OFF_BBAS = alignup(OFF_W1T  + 64*256*2);         // 129 int
static constexpr size_t OFF_RP   = alignup(OFF_BBAS + 132*4);            // (NN+1) int
static constexpr size_t OFF_SRC  = alignup(OFF_RP   + (size_t)(NN+1)*4); // ET int
static constexpr size_t OFF_BCUR = alignup(OFF_SRC  + (size_t)ET*4);     // 128 int
static constexpr size_t OFF_AGGH = alignup(OFF_BCUR + 128*4);            // N*512 fp16
static constexpr size_t OFF_BKT  = OFF_AGGH;                             // alias (disjoint lifetime)
static_assert((size_t)128 * BSLOT * 8 <= (size_t)NN * 512 * 2, "bkt fits in aggh");

__device__ inline void unpack8(float4 raw, float* g) {
  __half2* hp = (__half2*)&raw;
  float2 a = __half22float2(hp[0]); g[0] = a.x; g[1] = a.y;
  float2 b = __half22float2(hp[1]); g[2] = b.x; g[3] = b.y;
  float2 c = __half22float2(hp[2]); g[4] = c.x; g[5] = c.y;
  float2 d = __half22float2(hp[3]); g[6] = d.x; g[7] = d.y;
}

// half-pair builders: (b.lo, a.lo) and (b.hi, a.hi)
__device__ inline unsigned permb_lo(unsigned a, unsigned b) {
#if __has_builtin(__builtin_amdgcn_perm)
  return __builtin_amdgcn_perm(a, b, 0x05040100u);
#else
  return (b & 0xffffu) | (a << 16);
#endif
}
__device__ inline unsigned permb_hi(unsigned a, unsigned b) {
#if __has_builtin(__builtin_amdgcn_perm)
  return __builtin_amdgcn_perm(a, b, 0x07060302u);
#else
  return (b >> 16) | (a & 0xffff0000u);
#endif
}

// dot2: c + w.lo*g.lo + w.hi*g.hi  (f16 inputs, f32 accumulate)
__device__ inline float dot2h(unsigned w, unsigned g, float c) {
#if __has_builtin(__builtin_amdgcn_fdot2)
  union { unsigned u; h2_t h; } uw, ug;
  uw.u = w; ug.u = g;
  return __builtin_amdgcn_fdot2(uw.h, ug.h, c, false);
#else
  union { unsigned u; __half2 h; } uw, ug;
  uw.u = w; ug.u = g;
  float2 fw = __half22float2(uw.h), fg = __half22float2(ug.h);
  return c + fw.x * fg.x + fw.y * fg.y;
#endif
}

// ---------------- fused prep: W1t + W2t + wsd2 + bcur init -------------------
__global__ void k_prep(const float* __restrict__ W1, const float* __restrict__ W2,
                       const float* __restrict__ a_src2, const float* __restrict__ a_dst2,
                       _Float16* __restrict__ W1t, _Float16* __restrict__ W2t,
                       float* __restrict__ wsd2, int* __restrict__ bcur) {
  int t = blockIdx.x * 256 + threadIdx.x;
  if (t < 64 * 256) {
    int f = t >> 8, k = t & 255;
    W1t[t] = (_Float16)W1[k * 64 + f];
  }
  {
    int f = t >> 9, k = t & 511;
    int h = k >> 6, kk = k & 63;
    W2t[t] = (_Float16)W2[kk * 512 + h * 64 + f];
  }
  if (t < 1024) {
    int k = t >> 4, j = t & 15, h = j & 7;
    const float* av = (j < 8) ? a_src2 : a_dst2;
    float s = 0.f;
    for (int f = 0; f < 64; f++) s += W2[k * 512 + h * 64 + f] * av[h * 64 + f];
    wsd2[t] = s;
  }
  if (t < 128) bcur[t] = t * BSLOT;   // per-bucket slot base
}

// ---------------- F1: edge-partition (blocks 0..NPB) || GEMM1 (rest) --------
// Independent work fused into one dispatch so the in-order stream overlaps
// them: k_part's ~25us hides under the MFMA GEMM.
__global__ __launch_bounds__(256) void k_f1(const float* __restrict__ x,
                                            const _Float16* __restrict__ W1t,
                                            __half* __restrict__ h1h,
                                            const int* __restrict__ edge,
                                            int* __restrict__ bcur,
                                            unsigned long long* __restrict__ bkt) {
  if (blockIdx.x < NPB) {
    // ---- k_part body (byte-identical; bcur pre-set to slot bases) ----
    __shared__ int lcnt[128];
    __shared__ int lbase[128];
    __shared__ int loff[128];
    const int t = threadIdx.x;
    const int e0 = blockIdx.x * PCH;
    if (t < 128) { lcnt[t] = 0; loff[t] = 0; }
    __syncthreads();
    for (int i = t; i < PCH; i += 256) {
      int e = e0 + i;
      if (e >= ET) break;
      int d = (e < EE) ? edge[EE + e] : (e - EE);
      atomicAdd(&lcnt[d >> 10], 1);
    }
    __syncthreads();
    if (t < 128 && lcnt[t] > 0) lbase[t] = atomicAdd(&bcur[t], lcnt[t]);
    __syncthreads();
    for (int i = t; i < PCH; i += 256) {
      int e = e0 + i;
      if (e >= ET) break;
      int s, d;
      if (e < EE) { s = edge[e]; d = edge[EE + e]; } else { s = e - EE; d = s; }
      int b = d >> 10;
      int off = atomicAdd(&loff[b], 1);
      bkt[(size_t)lbase[b] + off] = ((unsigned long long)d << 32) | (unsigned)s;
    }
    return;
  }
  // ---- gemm1m body ----
  const int bid = blockIdx.x - NPB;
  const int lane = threadIdx.x & 63;
  const int wv = threadIdx.x >> 6;
  const int m16 = lane & 15;
  const int q = lane >> 4;
  const int row = bid * 64 + wv * 16 + m16;
  const bool rok = row < NN;
  const float* xr = x + (size_t)row * 256 + q * 8;
  f32x4 c0 = {0.f, 0.f, 0.f, 0.f}, c1 = c0, c2 = c0, c3 = c0;
#pragma unroll
  for (int k0 = 0; k0 < 256; k0 += 32) {
    half8_t a;
    if (rok) {
      float4 xa = ((const float4*)(xr + k0))[0];
      float4 xb = ((const float4*)(xr + k0))[1];
      a[0] = (_Float16)xa.x; a[1] = (_Float16)xa.y;
      a[2] = (_Float16)xa.z; a[3] = (_Float16)xa.w;
      a[4] = (_Float16)xb.x; a[5] = (_Float16)xb.y;
      a[6] = (_Float16)xb.z; a[7] = (_Float16)xb.w;
    } else {
#pragma unroll
      for (int i = 0; i < 8; i++) a[i] = (_Float16)0.f;
    }
    half8_t b0 = *((const half8_t*)(W1t + (size_t)(0 * 16 + m16) * 256 + k0 + q * 8));
    half8_t b1 = *((const half8_t*)(W1t + (size_t)(1 * 16 + m16) * 256 + k0 + q * 8));
    half8_t b2 = *((const half8_t*)(W1t + (size_t)(2 * 16 + m16) * 256 + k0 + q * 8));
    half8_t b3 = *((const half8_t*)(W1t + (size_t)(3 * 16 + m16) * 256 + k0 + q * 8));
    c0 = __builtin_amdgcn_mfma_f32_16x16x32_f16(a, b0, c0, 0, 0, 0);
    c1 = __builtin_amdgcn_mfma_f32_16x16x32_f16(a, b1, c1, 0, 0, 0);
    c2 = __builtin_amdgcn_mfma_f32_16x16x32_f16(a, b2, c2, 0, 0, 0);
    c3 = __builtin_amdgcn_mfma_f32_16x16x32_f16(a, b3, c3, 0, 0, 0);
  }
#pragma unroll
  for (int r = 0; r < 4; r++) {
    int orow = bid * 64 + wv * 16 + q * 4 + r;
    if (orow >= NN) continue;
    __half* op = h1h + (size_t)orow * 64;
    op[0 * 16 + m16] = __float2half(c0[r]);
    op[1 * 16 + m16] = __float2half(c1[r]);
    op[2 * 16 + m16] = __float2half(c2[r]);
    op[3 * 16 + m16] = __float2half(c3[r]);
  }
}

// ---------------- F2: alpha1h (blocks 0..A1B) || bucket prefix (last block) --
__global__ __launch_bounds__(256) void k_f2(const __half* __restrict__ h1h,
                                            const float* __restrict__ a_src1,
                                            const float* __restrict__ a_dst1,
                                            __half* __restrict__ as1h,
                                            float* __restrict__ ad1,
                                            const int* __restrict__ bcur,
                                            int* __restrict__ bbase) {
  if (blockIdx.x == A1B) {
    // ---- binpfx body: cnt_c = bcur[c] - c*BSLOT ----
    int t = threadIdx.x;
    if (t > 128) return;
    int run = 0;
    for (int c = 0; c < 128; c++)
      if (c < t) run += bcur[c] - c * BSLOT;
    bbase[t] = run;            // bbase[128] = ET
    return;
  }
  int g = blockIdx.x * 256 + threadIdx.x;
  int n = g >> 3, h = g & 7;
  float4 raw = *((const float4*)&h1h[(size_t)n * 64 + h * 8]);
  float v[8];
  unpack8(raw, v);
  float s = 0.f, d = 0.f;
#pragma unroll
  for (int f = 0; f < 8; f++) {
    s += v[f] * a_src1[h * 8 + f];
    d += v[f] * a_dst1[h * 8 + f];
  }
  as1h[g] = __float2half(s);
  ad1[g] = d;
}

// ---------------- per-bucket LDS finalize -> rp + ssrc ----------------------
// Reads slotted region bkt[b*BSLOT .. +cnt); writes globally-contiguous
// rp/ssrc via bbase prefix.
__global__ __launch_bounds__(1024) void k_bsort(const unsigned long long* __restrict__ bkt,
                                                const int* __restrict__ bbase,
                                                int* __restrict__ rp,
                                                int* __restrict__ ssrc) {
  __shared__ int lh[1024];
  __shared__ int lc[1024];
  const int t = threadIdx.x;
  const int b = blockIdx.x;             // 0..127
  const int base = bbase[b];
  const int cnt = bbase[b + 1] - base;
  const size_t bin = (size_t)b * BSLOT;
  const int d0 = b << 10;
  lh[t] = 0;
  __syncthreads();
  for (int i = t; i < cnt; i += 1024)
    atomicAdd(&lh[(int)(bkt[bin + i] >> 32) - d0], 1);
  __syncthreads();
  int v = lh[t];                        // this dst's count
  for (int off = 1; off < 1024; off <<= 1) {
    __syncthreads();
    int a = (t >= off) ? lh[t - off] : 0;
    __syncthreads();
    lh[t] += a;
  }
  __syncthreads();
  int excl = base + lh[t] - v;          // exclusive prefix (global position)
  lc[t] = excl;
  int d = d0 + t;
  if (d < NN) rp[d] = excl;
  if (b == 0 && t == 0) rp[NN] = ET;
  __syncthreads();
  for (int i = t; i < cnt; i += 1024) {
    unsigned long long e = bkt[bin + i];
    int pos = atomicAdd(&lc[(int)(e >> 32) - d0], 1);
    ssrc[pos] = (int)(e & 0xffffffffu);
  }
}

// ---------------- layer-1 aggregation: 16 lanes per dst, 8-edge chunks ------
// (round-7 structure, byte-identical: measured best for aggB1)
__global__ __launch_bounds__(256) void k_aggB1(
    const __half* __restrict__ h1h, const __half* __restrict__ as1h,
    const float* __restrict__ ad1, const float* __restrict__ b1,
    const int* __restrict__ rp, const int* __restrict__ ssrc,
    const float* __restrict__ wsd2,
    __half* __restrict__ heluh, __half* __restrict__ as2h, float* __restrict__ ad2) {
  __shared__ float lds_w[1024];     // wsd2 staged once per block
  __shared__ float lds_v[16][68];   // per-group ELU output (padded)
  const int t = threadIdx.x;
  const int lane = t & 63;
  const int wv = t >> 6;
  const int gl = lane & 15;
  const int grp = lane >> 4;
  const int gi = wv * 4 + grp;
  const int d = blockIdx.x * 16 + gi;    // grid is exactly NN/16 -> no guard
#pragma unroll
  for (int i = 0; i < 4; i++) lds_w[t + i * 256] = wsd2[t + i * 256];
  __syncthreads();
  const int h = gl >> 1;                 // head owned by this lane
  const int hsrc = (lane & 48) | h;      // group-base | head lane
  const float adv = (gl < 8) ? ad1[d * 8 + gl] : 0.f;
  const int r0 = rp[d], r1 = rp[d + 1];
  float acc0 = 0.f, acc1 = 0.f, acc2 = 0.f, acc3 = 0.f;
  float lsum = 0.f;
  const __half* gp = h1h + gl * 4;
  const __half* ap = as1h + gl;
  for (int e = r0; e < r1; e += 8) {
    int ss[8];
#pragma unroll
    for (int k = 0; k < 8; k++) {
      int idx = e + k;
      ss[k] = ssrc[(idx < r1) ? idx : (r1 - 1)];
    }
    union { float2 f; unsigned u[2]; } raws[8];
#pragma unroll
    for (int k = 0; k < 8; k++) raws[k].f = *((const float2*)(gp + (size_t)ss[k] * 64));
    unsigned wp[4];
    if (gl < 8) {
      float pv[8];
#pragma unroll
      for (int k = 0; k < 8; k++) {
        float tt = __half2float(ap[ss[k] * 8]) + adv;
        tt = tt > 0.f ? tt : NEG * tt;
        pv[k] = (e + k < r1) ? __expf(tt) : 0.f;
      }
#pragma unroll
      for (int j = 0; j < 4; j++) {
        __half2 ph = __floats2half2_rn(pv[2 * j], pv[2 * j + 1]);
        union { __half2 h2; unsigned u; } uw; uw.h2 = ph;
        wp[j] = uw.u;
        float2 pb = __half22float2(ph);
        lsum += pb.x + pb.y;
      }
    } else {
#pragma unroll
      for (int j = 0; j < 4; j++) wp[j] = 0;
    }
#pragma unroll
    for (int j = 0; j < 4; j++) {
      unsigned w = (unsigned)__shfl((int)wp[j], hsrc, 64);
      unsigned pr0 = permb_lo(raws[2 * j + 1].u[0], raws[2 * j].u[0]);
      unsigned pr1 = permb_hi(raws[2 * j + 1].u[0], raws[2 * j].u[0]);
      unsigned pr2 = permb_lo(raws[2 * j + 1].u[1], raws[2 * j].u[1]);
      unsigned pr3 = permb_hi(raws[2 * j + 1].u[1], raws[2 * j].u[1]);
      acc0 = dot2h(w, pr0, acc0);
      acc1 = dot2h(w, pr1, acc1);
      acc2 = dot2h(w, pr2, acc2);
      acc3 = dot2h(w, pr3, acc3);
    }
  }
  float lv = __shfl(lsum, hsrc, 64);
  float rl = 1.f / lv;
  float v0 = acc0 * rl + b1[gl * 4 + 0];
  float v1 = acc1 * rl + b1[gl * 4 + 1];
  float v2 = acc2 * rl + b1[gl * 4 + 2];
  float v3 = acc3 * rl + b1[gl * 4 + 3];
  v0 = v0 > 0.f ? v0 : __expf(v0) - 1.f;   // ELU
  v1 = v1 > 0.f ? v1 : __expf(v1) - 1.f;
  v2 = v2 > 0.f ? v2 : __expf(v2) - 1.f;
  v3 = v3 > 0.f ? v3 : __expf(v3) - 1.f;
  union { __half2 h2[2]; float2 f2; } u;
  u.h2[0] = __floats2half2_rn(v0, v1);
  u.h2[1] = __floats2half2_rn(v2, v3);
  *((float2*)&heluh[(size_t)d * 64 + gl * 4]) = u.f2;
  lds_v[gi][gl * 4 + 0] = v0;
  lds_v[gi][gl * 4 + 1] = v1;
  lds_v[gi][gl * 4 + 2] = v2;
  lds_v[gi][gl * 4 + 3] = v3;
  float dot = 0.f;
#pragma unroll
  for (int f = 0; f < 64; f++) dot += lds_v[gi][f] * lds_w[f * 16 + gl];
  if (gl < 8) as2h[d * 8 + gl] = __float2half(dot);
  else        ad2[d * 8 + (gl & 7)] = dot;
}

// ---------------- layer-2 aggregation: 32 lanes per dst, 1-deep pipeline ----
// (round-7 structure, byte-identical: measured best)
__global__ __launch_bounds__(256) void k_aggB2(
    const __half* __restrict__ heluh, const __half* __restrict__ as2h,
    const float* __restrict__ ad2, const int* __restrict__ rp,
    const int* __restrict__ ssrc, __half* __restrict__ aggh) {
  const int lane = threadIdx.x & 63;
  const int wv = threadIdx.x >> 6;
  const int gl = lane & 31;
  const int fl = gl & 15;
  const int hh = (gl >> 4) * 4;          // head base: 0 or 4
  const int gb = lane & 32;              // group-base lane
  const int d = blockIdx.x * 8 + wv * 2 + (lane >> 5);  // grid exactly NN/8
  const float adv = (gl < 8) ? ad2[d * 8 + gl] : 0.f;
  const int r0 = rp[d], r1 = rp[d + 1];  // r1 > r0 always (self-loop)
  float acc[4][4];
#pragma unroll
  for (int j = 0; j < 4; j++)
#pragma unroll
    for (int k = 0; k < 4; k++) acc[j][k] = 0.f;
  float lsum = 0.f;
  const __half* gp = heluh + fl * 4;
  const __half* ap = as2h + gl;
  int s1c = min(r0 + 1, r1 - 1);
  union { float2 f; unsigned u[2]; } raw0, raw1, r0n, r1n;
  raw0.f = *((const float2*)(gp + (size_t)ssrc[r0] * 64));
  raw1.f = *((const float2*)(gp + (size_t)ssrc[s1c] * 64));
  __half lg0 = __float2half(0.f), lg1 = lg0, lg0n = lg0, lg1n = lg0;
  if (gl < 8) { lg0 = ap[(size_t)ssrc[r0] * 8]; lg1 = ap[(size_t)ssrc[s1c] * 8]; }
  for (int e = r0; e < r1; e += 2) {
    int np = e + 2;
    if (np < r1) {
      int sn0 = ssrc[np];
      int sn1 = ssrc[min(np + 1, r1 - 1)];
      r0n.f = *((const float2*)(gp + (size_t)sn0 * 64));
      r1n.f = *((const float2*)(gp + (size_t)sn1 * 64));
      if (gl < 8) { lg0n = ap[(size_t)sn0 * 8]; lg1n = ap[(size_t)sn1 * 8]; }
    }
    unsigned wpack = 0;
    if (gl < 8) {
      float t0 = __half2float(lg0) + adv;
      float t1 = __half2float(lg1) + adv;
      t0 = t0 > 0.f ? t0 : NEG * t0;
      t1 = t1 > 0.f ? t1 : NEG * t1;
      float p0 = __expf(t0);
      float p1 = (e + 1 < r1) ? __expf(t1) : 0.f;
      __half2 ph = __floats2half2_rn(p0, p1);
      union { __half2 h2; unsigned u; } uw; uw.h2 = ph;
      wpack = uw.u;
      float2 pb = __half22float2(ph);
      lsum += pb.x + pb.y;
    }
    unsigned pr0 = permb_lo(raw1.u[0], raw0.u[0]);  // (g0 f0, g1 f0)
    unsigned pr1 = permb_hi(raw1.u[0], raw0.u[0]);
    unsigned pr2 = permb_lo(raw1.u[1], raw0.u[1]);
    unsigned pr3 = permb_hi(raw1.u[1], raw0.u[1]);
#pragma unroll
    for (int j = 0; j < 4; j++) {
      unsigned w = (unsigned)__shfl((int)wpack, gb | (hh + j), 64);
      acc[j][0] = dot2h(w, pr0, acc[j][0]);
      acc[j][1] = dot2h(w, pr1, acc[j][1]);
      acc[j][2] = dot2h(w, pr2, acc[j][2]);
      acc[j][3] = dot2h(w, pr3, acc[j][3]);
    }
    raw0 = r0n; raw1 = r1n; lg0 = lg0n; lg1 = lg1n;
  }
#pragma unroll
  for (int j = 0; j < 4; j++) {
    float lv = __shfl(lsum, gb | (hh + j), 64);
    float rl = 1.f / lv;
    union { __half2 h2[2]; float2 f2; } u;
    u.h2[0] = __floats2half2_rn(acc[j][0] * rl, acc[j][1] * rl);
    u.h2[1] = __floats2half2_rn(acc[j][2] * rl, acc[j][3] * rl);
    *((float2*)&aggh[(size_t)d * 512 + (hh + j) * 64 + fl * 4]) = u.f2;
  }
}

// ---------------- GEMM2 via MFMA: out = (1/8)*aggh[N,512] @ W2t^T + b2 -------
__global__ __launch_bounds__(256) void k_gemm2m(const __half* __restrict__ aggh,
                                                const _Float16* __restrict__ W2t,
                                                const float* __restrict__ b2,
                                                float* __restrict__ out) {
  const int lane = threadIdx.x & 63;
  const int wv = threadIdx.x >> 6;
  const int m16 = lane & 15;
  const int q = lane >> 4;
  const int row = blockIdx.x * 64 + wv * 16 + m16;
  const bool rok = row < NN;
  const _Float16* arow = (const _Float16*)aggh + (size_t)row * 512 + q * 8;
  half8_t zero8;
#pragma unroll
  for (int i = 0; i < 8; i++) zero8[i] = (_Float16)0.f;
  f32x4 c0 = {0.f, 0.f, 0.f, 0.f}, c1 = c0, c2 = c0, c3 = c0;
#pragma unroll
  for (int k0 = 0; k0 < 512; k0 += 32) {
    half8_t a = rok ? *((const half8_t*)(arow + k0)) : zero8;
    half8_t b0 = *((const half8_t*)(W2t + (size_t)(0 * 16 + m16) * 512 + k0 + q * 8));
    half8_t b1 = *((const half8_t*)(W2t + (size_t)(1 * 16 + m16) * 512 + k0 + q * 8));
    half8_t b2f = *((const half8_t*)(W2t + (size_t)(2 * 16 + m16) * 512 + k0 + q * 8));
    half8_t b3 = *((const half8_t*)(W2t + (size_t)(3 * 16 + m16) * 512 + k0 + q * 8));
    c0 = __builtin_amdgcn_mfma_f32_16x16x32_f16(a, b0, c0, 0, 0, 0);
    c1 = __builtin_amdgcn_mfma_f32_16x16x32_f16(a, b1, c1, 0, 0, 0);
    c2 = __builtin_amdgcn_mfma_f32_16x16x32_f16(a, b2f, c2, 0, 0, 0);
    c3 = __builtin_amdgcn_mfma_f32_16x16x32_f16(a, b3, c3, 0, 0, 0);
  }
  float bias0 = b2[0 * 16 + m16];
  float bias1 = b2[1 * 16 + m16];
  float bias2 = b2[2 * 16 + m16];
  float bias3 = b2[3 * 16 + m16];
#pragma unroll
  for (int r = 0; r < 4; r++) {
    int orow = blockIdx.x * 64 + wv * 16 + q * 4 + r;
    if (orow >= NN) continue;
    float* op = out + (size_t)orow * 64;
    op[0 * 16 + m16] = 0.125f * c0[r] + bias0;
    op[1 * 16 + m16] = 0.125f * c1[r] + bias1;
    op[2 * 16 + m16] = 0.125f * c2[r] + bias2;
    op[3 * 16 + m16] = 0.125f * c3[r] + bias3;
  }
}

extern "C" void kernel_launch(void* const* d_in, const int* in_sizes, int n_in,
                              void* d_out, int out_size, void* d_ws, size_t ws_size,
                              hipStream_t stream) {
  const float* x      = (const float*)d_in[0];
  const float* W1     = (const float*)d_in[1];
  const float* a_src1 = (const float*)d_in[2];
  const float* a_dst1 = (const float*)d_in[3];
  const float* b1     = (const float*)d_in[4];
  const float* W2     = (const float*)d_in[5];
  const float* a_src2 = (const float*)d_in[6];
  const float* a_dst2 = (const float*)d_in[7];
  const float* b2     = (const float*)d_in[8];
  const int*   edge   = (const int*)d_in[9];

  char* ws = (char*)d_ws;
  __half* h1h   = (__half*)(ws + OFF_H1H);
  __half* heluh = (__half*)(ws + OFF_HELU);
  __half* as1h  = (__half*)(ws + OFF_AS1H);
  float*  ad1   = (float*)(ws + OFF_AD1);
  __half* as2h  = (__half*)(ws + OFF_AS2H);
  float*  ad2   = (float*)(ws + OFF_AD2);
  float*  wsd2  = (float*)(ws + OFF_WSD2);
  _Float16* W2t = (_Float16*)(ws + OFF_W2T);
  _Float16* W1t = (_Float16*)(ws + OFF_W1T);
  int* bbase  = (int*)(ws + OFF_BBAS);
  int* rp     = (int*)(ws + OFF_RP);
  int* ssrc   = (int*)(ws + OFF_SRC);
  int* bcur   = (int*)(ws + OFF_BCUR);
  unsigned long long* bkt = (unsigned long long*)(ws + OFF_BKT);
  __half* aggh = (__half*)(ws + OFF_AGGH);
  float* out  = (float*)d_out;

  k_prep<<<128, 256, 0, stream>>>(W1, W2, a_src2, a_dst2, W1t, W2t, wsd2, bcur);
  k_f1<<<NPB + G1B, 256, 0, stream>>>(x, W1t, h1h, edge, bcur, bkt);
  k_f2<<<A1B + 1, 256, 0, stream>>>(h1h, a_src1, a_dst1, as1h, ad1, bcur, bbase);
  k_bsort<<<128, 1024, 0, stream>>>(bkt, bbase, rp, ssrc);
  k_aggB1<<<NN / 16, 256, 0, stream>>>(h1h, as1h, ad1, b1, rp, ssrc, wsd2, heluh, as2h, ad2);
  k_aggB2<<<NN / 8, 256, 0, stream>>>(heluh, as2h, ad2, rp, ssrc, aggh);
  k_gemm2m<<<(NN + 63) / 64, 256, 0, stream>>>(aggh, W2t, b2, out);
}